// Round 1
// baseline (1548.132 us; speedup 1.0000x reference)
//
#include <hip/hip_runtime.h>
#include <cstdint>
#include <cmath>

#define BB   2
#define NN   2048
#define DIMM 1024
#define NHH  16
#define DHH  64
#define MMR  (BB * NN)  // 4096 rows for projections

typedef _Float16 half8  __attribute__((ext_vector_type(8)));
typedef _Float16 half4v __attribute__((ext_vector_type(4)));
typedef float    f32x4  __attribute__((ext_vector_type(4)));

// ---------------- convert x (fp32 -> f16) ----------------
__global__ __launch_bounds__(256) void cvt_x_kernel(const float* __restrict__ x,
                                                    _Float16* __restrict__ xh) {
  int i = (blockIdx.x * 256 + threadIdx.x) * 4;
  float4 v = *(const float4*)(x + i);
  half4v h;
  h[0] = (_Float16)v.x; h[1] = (_Float16)v.y;
  h[2] = (_Float16)v.z; h[3] = (_Float16)v.w;
  *(half4v*)(xh + i) = h;
}

// ---------------- transpose + convert weights: W[k][n] -> Wt[n][k] f16 ----------------
__global__ __launch_bounds__(256) void transpose_w_kernel(
    const float* __restrict__ Wq, const float* __restrict__ Wk,
    const float* __restrict__ Wv, const float* __restrict__ Wo,
    _Float16* __restrict__ wt) {
  __shared__ float tile[64][65];
  int z = blockIdx.z;
  const float* W = (z == 0) ? Wq : (z == 1) ? Wk : (z == 2) ? Wv : Wo;
  _Float16* dst = wt + (size_t)z * 1024 * 1024;
  int r0 = blockIdx.x * 64;  // k block
  int c0 = blockIdx.y * 64;  // n block
  int t = threadIdx.x;
  int tr = t >> 4;           // 0..15
  int tc = (t & 15) * 4;     // 0..60
#pragma unroll
  for (int i = 0; i < 4; ++i) {
    float4 v = *(const float4*)(W + (size_t)(r0 + tr + i * 16) * 1024 + c0 + tc);
    tile[tr + i * 16][tc + 0] = v.x;
    tile[tr + i * 16][tc + 1] = v.y;
    tile[tr + i * 16][tc + 2] = v.z;
    tile[tr + i * 16][tc + 3] = v.w;
  }
  __syncthreads();
#pragma unroll
  for (int i = 0; i < 4; ++i) {
    int nl = tr + i * 16;
    half4v hv;
    hv[0] = (_Float16)tile[tc + 0][nl];
    hv[1] = (_Float16)tile[tc + 1][nl];
    hv[2] = (_Float16)tile[tc + 2][nl];
    hv[3] = (_Float16)tile[tc + 3][nl];
    *(half4v*)(dst + (size_t)(c0 + nl) * 1024 + r0 + tc) = hv;
  }
}

// ---------------- QKV GEMM (MFMA f16) + RoPE epilogue ----------------
// grid: (M/64, 3*1024/64) ; block 256 (4 waves)
// wave w: rows w*16..w*16+15 of the 64x64 tile, 4 column frags of 16.
__global__ __launch_bounds__(256) void gemm_qkv_kernel(
    const _Float16* __restrict__ xh, const _Float16* __restrict__ wt,
    float* __restrict__ qo, float* __restrict__ ko, float* __restrict__ vo) {
  __shared__ _Float16 At[64][40];  // pad to 40 halfs (80B): frag reads 2-way only
  __shared__ _Float16 Bt[64][40];
  __shared__ float Cs[64][65];
  int m0  = blockIdx.x * 64;
  int ngl = blockIdx.y * 64;
  int mat = ngl >> 10;     // 0=q 1=k 2=v
  int n0  = ngl & 1023;    // col within matrix
  const _Float16* wb = wt + (size_t)mat * 1024 * 1024;
  int t = threadIdx.x;
  int wv = t >> 6;
  int lane = t & 63;
  int l16 = lane & 15;
  int quad = lane >> 4;
  int sr = t >> 2;          // stage row 0..63
  int sc = (t & 3) * 8;     // stage col chunk
  f32x4 acc[4] = {};
  const _Float16* ap = xh + (size_t)(m0 + sr) * 1024 + sc;
  const _Float16* bp = wb + (size_t)(n0 + sr) * 1024 + sc;
  for (int k0 = 0; k0 < 1024; k0 += 32) {
    half8 av = *(const half8*)(ap + k0);
    half8 bv = *(const half8*)(bp + k0);
    *(half8*)(&At[sr][sc]) = av;
    *(half8*)(&Bt[sr][sc]) = bv;
    __syncthreads();
    half8 af = *(const half8*)(&At[wv * 16 + l16][quad * 8]);
#pragma unroll
    for (int nt = 0; nt < 4; ++nt) {
      half8 bf = *(const half8*)(&Bt[nt * 16 + l16][quad * 8]);
      acc[nt] = __builtin_amdgcn_mfma_f32_16x16x32_f16(af, bf, acc[nt], 0, 0, 0);
    }
    __syncthreads();
  }
  // C frags -> LDS (D layout: row = quad*4+reg, col = l16)
#pragma unroll
  for (int nt = 0; nt < 4; ++nt)
#pragma unroll
    for (int r = 0; r < 4; ++r)
      Cs[wv * 16 + quad * 4 + r][nt * 16 + l16] = acc[nt][r];
  __syncthreads();
  // epilogue: thread t -> row t/4, 16 cols at (t%4)*16
  int lr = t >> 2;
  int cseg = (t & 3) * 16;
  int m = m0 + lr;
  int b = m >> 11;          // / 2048
  int pos = m & 2047;
  int h = n0 >> 6;          // head (n0 multiple of 64)
  float vals[16];
  if (mat == 2) {
#pragma unroll
    for (int j = 0; j < 16; ++j) vals[j] = Cs[lr][cseg + j];
  } else {
    float fpos = (float)pos;
#pragma unroll
    for (int j = 0; j < 16; ++j) {
      int i = cseg + j;
      int jd = (i < 32) ? i : (i - 32);
      // inv_freq = 10000^(-jd/32) = 2^(-jd * log2(10000)/32)
      float invf = exp2f((float)jd * -0.41524101186092029f);
      float ang = fpos * invf;
      float sv, cv;
      sincosf(ang, &sv, &cv);
      float partner = (i < 32) ? -Cs[lr][2 * i + 1] : Cs[lr][2 * (i - 32)];
      vals[j] = Cs[lr][i] * cv + partner * sv;
    }
  }
  float* dst = (mat == 0) ? qo : (mat == 1) ? ko : vo;
  size_t ob = ((size_t)(b * NHH + h) * NN + pos) * DHH + cseg;
#pragma unroll
  for (int j4 = 0; j4 < 4; ++j4) {
    float4 o;
    o.x = vals[j4 * 4 + 0]; o.y = vals[j4 * 4 + 1];
    o.z = vals[j4 * 4 + 2]; o.w = vals[j4 * 4 + 3];
    *(float4*)(dst + ob + j4 * 4) = o;
  }
}

// ---------------- causal flash attention, fp32 vector ----------------
// grid 512 (bh*16+qb), block 128; thread = one q row; K/V 64-row tiles in LDS.
__global__ __launch_bounds__(128) void attn_kernel(
    const float* __restrict__ qg, const float* __restrict__ kg,
    const float* __restrict__ vg, _Float16* __restrict__ attnh) {
  __shared__ float Kt[64][68];
  __shared__ float Vt[64][68];
  int bx = blockIdx.x;
  int bh = bx >> 4;   // 0..31
  int qb = bx & 15;   // 0..15
  int t = threadIdx.x;
  int r = qb * 128 + t;  // query position 0..2047
  float q[64], acc[64];
  size_t qbase = ((size_t)bh * NN + r) * DHH;
#pragma unroll
  for (int d4 = 0; d4 < 16; ++d4) {
    float4 v = *(const float4*)(qg + qbase + d4 * 4);
    q[d4 * 4 + 0] = v.x; q[d4 * 4 + 1] = v.y;
    q[d4 * 4 + 2] = v.z; q[d4 * 4 + 3] = v.w;
  }
#pragma unroll
  for (int d = 0; d < 64; ++d) acc[d] = 0.f;
  float mval = -INFINITY, lsum = 0.f;
  int ktiles = (qb + 1) * 2;
  int str = t >> 1;          // 0..63
  int stc = (t & 1) * 32;    // 0 / 32
  for (int kt = 0; kt < ktiles; ++kt) {
    int kbase = kt * 64;
    __syncthreads();
    size_t gb = ((size_t)bh * NN + kbase + str) * DHH + stc;
#pragma unroll
    for (int j = 0; j < 8; ++j) {
      *(float4*)&Kt[str][stc + j * 4] = *(const float4*)(kg + gb + j * 4);
      *(float4*)&Vt[str][stc + j * 4] = *(const float4*)(vg + gb + j * 4);
    }
    __syncthreads();
    int kend = r - kbase + 1;
    if (kend > 64) kend = 64;
    for (int kk = 0; kk < kend; ++kk) {
      float s0 = 0.f, s1 = 0.f, s2 = 0.f, s3 = 0.f;
#pragma unroll
      for (int d4 = 0; d4 < 16; ++d4) {
        float4 kv = *(const float4*)&Kt[kk][d4 * 4];
        s0 = fmaf(q[d4 * 4 + 0], kv.x, s0);
        s1 = fmaf(q[d4 * 4 + 1], kv.y, s1);
        s2 = fmaf(q[d4 * 4 + 2], kv.z, s2);
        s3 = fmaf(q[d4 * 4 + 3], kv.w, s3);
      }
      float s = ((s0 + s1) + (s2 + s3)) * 0.125f;
      float mnew = fmaxf(mval, s);
      float alpha = __expf(mval - mnew);
      float p = __expf(s - mnew);
      lsum = lsum * alpha + p;
      mval = mnew;
#pragma unroll
      for (int d4 = 0; d4 < 16; ++d4) {
        float4 vv = *(const float4*)&Vt[kk][d4 * 4];
        acc[d4 * 4 + 0] = fmaf(acc[d4 * 4 + 0], alpha, p * vv.x);
        acc[d4 * 4 + 1] = fmaf(acc[d4 * 4 + 1], alpha, p * vv.y);
        acc[d4 * 4 + 2] = fmaf(acc[d4 * 4 + 2], alpha, p * vv.z);
        acc[d4 * 4 + 3] = fmaf(acc[d4 * 4 + 3], alpha, p * vv.w);
      }
    }
  }
  float inv = 1.f / lsum;
  int b = bh >> 4, h = bh & 15;
  size_t ob = ((size_t)(b * NN + r)) * 1024 + h * 64;  // attn (m, inner) layout
#pragma unroll
  for (int d8 = 0; d8 < 8; ++d8) {
    half8 hv;
#pragma unroll
    for (int c = 0; c < 8; ++c) hv[c] = (_Float16)(acc[d8 * 8 + c] * inv);
    *(half8*)(attnh + ob + d8 * 8) = hv;
  }
}

// ---------------- out GEMM (MFMA f16) + bias ----------------
__global__ __launch_bounds__(256) void gemm_out_kernel(
    const _Float16* __restrict__ ah, const _Float16* __restrict__ wot,
    const float* __restrict__ bo, float* __restrict__ out) {
  __shared__ _Float16 At[64][40];
  __shared__ _Float16 Bt[64][40];
  int m0 = blockIdx.x * 64;
  int n0 = blockIdx.y * 64;
  int t = threadIdx.x;
  int wv = t >> 6;
  int lane = t & 63;
  int l16 = lane & 15;
  int quad = lane >> 4;
  int sr = t >> 2;
  int sc = (t & 3) * 8;
  f32x4 acc[4] = {};
  const _Float16* ap = ah + (size_t)(m0 + sr) * 1024 + sc;
  const _Float16* bp = wot + (size_t)(n0 + sr) * 1024 + sc;
  for (int k0 = 0; k0 < 1024; k0 += 32) {
    half8 av = *(const half8*)(ap + k0);
    half8 bv = *(const half8*)(bp + k0);
    *(half8*)(&At[sr][sc]) = av;
    *(half8*)(&Bt[sr][sc]) = bv;
    __syncthreads();
    half8 af = *(const half8*)(&At[wv * 16 + l16][quad * 8]);
#pragma unroll
    for (int nt = 0; nt < 4; ++nt) {
      half8 bf = *(const half8*)(&Bt[nt * 16 + l16][quad * 8]);
      acc[nt] = __builtin_amdgcn_mfma_f32_16x16x32_f16(af, bf, acc[nt], 0, 0, 0);
    }
    __syncthreads();
  }
#pragma unroll
  for (int nt = 0; nt < 4; ++nt) {
    int col = n0 + nt * 16 + l16;
    float bias = bo[col];
#pragma unroll
    for (int rr = 0; rr < 4; ++rr) {
      out[(size_t)(m0 + wv * 16 + quad * 4 + rr) * 1024 + col] = acc[nt][rr] + bias;
    }
  }
}

extern "C" void kernel_launch(void* const* d_in, const int* in_sizes, int n_in,
                              void* d_out, int out_size, void* d_ws, size_t ws_size,
                              hipStream_t stream) {
  (void)in_sizes; (void)n_in; (void)out_size; (void)ws_size;
  const float* x  = (const float*)d_in[0];
  const float* Wq = (const float*)d_in[1];
  const float* Wk = (const float*)d_in[2];
  const float* Wv = (const float*)d_in[3];
  const float* Wo = (const float*)d_in[4];
  const float* bo = (const float*)d_in[5];

  float* out = (float*)d_out;                       // (B,N,DIM)
  float* ko  = out + (size_t)MMR * DIMM;            // (B,H,N,DH)
  float* vo  = ko + (size_t)BB * NHH * NN * DHH;    // (B,H,N,DH)

  char* w = (char*)d_ws;
  _Float16* xh  = (_Float16*)w;                     // 8 MB
  _Float16* wt  = (_Float16*)(w + (8u << 20));      // 8 MB (Wq,Wk,Wv,Wo transposed f16)
  float*    qws = (float*)(w + (16u << 20));        // 16 MB rope'd q (b,h,n,dh)
  _Float16* ah  = (_Float16*)(w + (32u << 20));     // 8 MB attn (m, inner) f16

  hipLaunchKernelGGL(cvt_x_kernel, dim3(4096), dim3(256), 0, stream, x, xh);
  hipLaunchKernelGGL(transpose_w_kernel, dim3(16, 16, 4), dim3(256), 0, stream,
                     Wq, Wk, Wv, Wo, wt);
  hipLaunchKernelGGL(gemm_qkv_kernel, dim3(64, 48), dim3(256), 0, stream,
                     xh, wt, qws, ko, vo);
  hipLaunchKernelGGL(attn_kernel, dim3(512), dim3(128), 0, stream, qws, ko, vo, ah);
  hipLaunchKernelGGL(gemm_out_kernel, dim3(64, 16), dim3(256), 0, stream,
                     ah, wt + (size_t)3 * 1024 * 1024, bo, out);
}

// Round 2
// 305.459 us; speedup vs baseline: 5.0682x; 5.0682x over previous
//
#include <hip/hip_runtime.h>
#include <cstdint>
#include <cmath>

#define BB   2
#define NN   2048
#define DIMM 1024
#define NHH  16
#define DHH  64
#define MMR  (BB * NN)

typedef _Float16 half8  __attribute__((ext_vector_type(8)));
typedef _Float16 half4v __attribute__((ext_vector_type(4)));
typedef float    f32x4  __attribute__((ext_vector_type(4)));

// ---------------- convert x (fp32 -> f16) ----------------
__global__ __launch_bounds__(256) void cvt_x_kernel(const float* __restrict__ x,
                                                    _Float16* __restrict__ xh) {
  int i = (blockIdx.x * 256 + threadIdx.x) * 4;
  float4 v = *(const float4*)(x + i);
  half4v h;
  h[0] = (_Float16)v.x; h[1] = (_Float16)v.y;
  h[2] = (_Float16)v.z; h[3] = (_Float16)v.w;
  *(half4v*)(xh + i) = h;
}

// ---------------- transpose + convert weights: W[k][n] -> Wt[n][k] f16 ----------------
__global__ __launch_bounds__(256) void transpose_w_kernel(
    const float* __restrict__ Wq, const float* __restrict__ Wk,
    const float* __restrict__ Wv, const float* __restrict__ Wo,
    _Float16* __restrict__ wt) {
  __shared__ float tile[64][65];
  int z = blockIdx.z;
  const float* W = (z == 0) ? Wq : (z == 1) ? Wk : (z == 2) ? Wv : Wo;
  _Float16* dst = wt + (size_t)z * 1024 * 1024;
  int r0 = blockIdx.x * 64;
  int c0 = blockIdx.y * 64;
  int t = threadIdx.x;
  int tr = t >> 4;
  int tc = (t & 15) * 4;
#pragma unroll
  for (int i = 0; i < 4; ++i) {
    float4 v = *(const float4*)(W + (size_t)(r0 + tr + i * 16) * 1024 + c0 + tc);
    tile[tr + i * 16][tc + 0] = v.x;
    tile[tr + i * 16][tc + 1] = v.y;
    tile[tr + i * 16][tc + 2] = v.z;
    tile[tr + i * 16][tc + 3] = v.w;
  }
  __syncthreads();
#pragma unroll
  for (int i = 0; i < 4; ++i) {
    int nl = tr + i * 16;
    half4v hv;
    hv[0] = (_Float16)tile[tc + 0][nl];
    hv[1] = (_Float16)tile[tc + 1][nl];
    hv[2] = (_Float16)tile[tc + 2][nl];
    hv[3] = (_Float16)tile[tc + 3][nl];
    *(half4v*)(dst + (size_t)(c0 + nl) * 1024 + r0 + tc) = hv;
  }
}

// ---------------- QKV GEMM (MFMA f16) + RoPE epilogue ----------------
// grid (64, 48), block 256. Writes:
//   mat 0 (q): rope, *0.125, f16 -> qh (b,h,n,dh)
//   mat 1 (k): rope, f32 -> ko (output) + f16 -> kh (b,h,n,dh)
//   mat 2 (v): f32 -> vo (output) + f16 transposed -> vth (b,h,dh,n)
__global__ __launch_bounds__(256) void gemm_qkv_kernel(
    const _Float16* __restrict__ xh, const _Float16* __restrict__ wt,
    float* __restrict__ ko, float* __restrict__ vo,
    _Float16* __restrict__ qh, _Float16* __restrict__ kh,
    _Float16* __restrict__ vth) {
  __shared__ _Float16 At[64][40];
  __shared__ _Float16 Bt[64][40];
  __shared__ float Cs[64][65];
  int m0  = blockIdx.x * 64;
  int ngl = blockIdx.y * 64;
  int mat = ngl >> 10;
  int n0  = ngl & 1023;
  const _Float16* wb = wt + (size_t)mat * 1024 * 1024;
  int t = threadIdx.x;
  int wv = t >> 6;
  int lane = t & 63;
  int l16 = lane & 15;
  int quad = lane >> 4;
  int sr = t >> 2;
  int sc = (t & 3) * 8;
  f32x4 acc[4] = {};
  const _Float16* ap = xh + (size_t)(m0 + sr) * 1024 + sc;
  const _Float16* bp = wb + (size_t)(n0 + sr) * 1024 + sc;
  for (int k0 = 0; k0 < 1024; k0 += 32) {
    half8 av = *(const half8*)(ap + k0);
    half8 bv = *(const half8*)(bp + k0);
    *(half8*)(&At[sr][sc]) = av;
    *(half8*)(&Bt[sr][sc]) = bv;
    __syncthreads();
    half8 af = *(const half8*)(&At[wv * 16 + l16][quad * 8]);
#pragma unroll
    for (int nt = 0; nt < 4; ++nt) {
      half8 bf = *(const half8*)(&Bt[nt * 16 + l16][quad * 8]);
      acc[nt] = __builtin_amdgcn_mfma_f32_16x16x32_f16(af, bf, acc[nt], 0, 0, 0);
    }
    __syncthreads();
  }
#pragma unroll
  for (int nt = 0; nt < 4; ++nt)
#pragma unroll
    for (int r = 0; r < 4; ++r)
      Cs[wv * 16 + quad * 4 + r][nt * 16 + l16] = acc[nt][r];
  __syncthreads();
  int lr = t >> 2;
  int cseg = (t & 3) * 16;
  int m = m0 + lr;
  int b = m >> 11;
  int pos = m & 2047;
  int h = n0 >> 6;
  int bhh = b * NHH + h;
  float vals[16];
  if (mat == 2) {
#pragma unroll
    for (int j = 0; j < 16; ++j) vals[j] = Cs[lr][cseg + j];
  } else {
    float fpos = (float)pos;
#pragma unroll
    for (int j = 0; j < 16; ++j) {
      int i = cseg + j;
      int jd = (i < 32) ? i : (i - 32);
      float invf = exp2f((float)jd * -0.41524101186092029f);
      float ang = fpos * invf;
      float sv, cv;
      sincosf(ang, &sv, &cv);
      float partner = (i < 32) ? -Cs[lr][2 * i + 1] : Cs[lr][2 * (i - 32)];
      vals[j] = Cs[lr][i] * cv + partner * sv;
    }
  }
  size_t rowb = ((size_t)bhh * NN + pos) * DHH + cseg;
  if (mat == 0) {
    half8 h0, h1;
#pragma unroll
    for (int j = 0; j < 8; ++j) { h0[j] = (_Float16)(vals[j] * 0.125f); h1[j] = (_Float16)(vals[8 + j] * 0.125f); }
    *(half8*)(qh + rowb) = h0;
    *(half8*)(qh + rowb + 8) = h1;
  } else if (mat == 1) {
#pragma unroll
    for (int j4 = 0; j4 < 4; ++j4) {
      float4 o;
      o.x = vals[j4 * 4 + 0]; o.y = vals[j4 * 4 + 1];
      o.z = vals[j4 * 4 + 2]; o.w = vals[j4 * 4 + 3];
      *(float4*)(ko + rowb + j4 * 4) = o;
    }
    half8 h0, h1;
#pragma unroll
    for (int j = 0; j < 8; ++j) { h0[j] = (_Float16)vals[j]; h1[j] = (_Float16)vals[8 + j]; }
    *(half8*)(kh + rowb) = h0;
    *(half8*)(kh + rowb + 8) = h1;
  } else {
#pragma unroll
    for (int j4 = 0; j4 < 4; ++j4) {
      float4 o;
      o.x = vals[j4 * 4 + 0]; o.y = vals[j4 * 4 + 1];
      o.z = vals[j4 * 4 + 2]; o.w = vals[j4 * 4 + 3];
      *(float4*)(vo + rowb + j4 * 4) = o;
    }
#pragma unroll
    for (int j = 0; j < 16; ++j)
      vth[((size_t)bhh * DHH + cseg + j) * NN + pos] = (_Float16)vals[j];
  }
}

// ---------------- MFMA flash attention (causal), f16 ----------------
// grid (32 qtiles, 32 bh), block 256 (4 waves). Wave wv owns q rows
// q0 + wv*16 .. +15. K/V tiles of 64 keys staged in LDS; P round-trips
// through a per-wave LDS buffer (no barrier needed, wave-local).
__global__ __launch_bounds__(256) void fattn_kernel(
    const _Float16* __restrict__ qh, const _Float16* __restrict__ kh,
    const _Float16* __restrict__ vth, _Float16* __restrict__ ah) {
  __shared__ _Float16 Kt[64][72];
  __shared__ _Float16 Vt[64][72];
  __shared__ _Float16 Pb[64][72];
  int qi = 31 - blockIdx.x;   // heavy (long) q-tiles first
  int bh = blockIdx.y;
  int t = threadIdx.x;
  int wv = t >> 6, lane = t & 63, l16 = lane & 15, quad = lane >> 4;
  int q0 = qi * 64;
  const _Float16* qptr = qh + ((size_t)bh * NN + q0 + wv * 16 + l16) * DHH + quad * 8;
  half8 qf0 = *(const half8*)(qptr);
  half8 qf1 = *(const half8*)(qptr + 32);
  f32x4 o[4] = {};
  float mrow[4], lrow[4];
#pragma unroll
  for (int r = 0; r < 4; ++r) { mrow[r] = -1e30f; lrow[r] = 0.f; }
  int srow = t >> 2, scol = (t & 3) * 16;
  for (int kt = 0; kt <= qi; ++kt) {
    __syncthreads();
    {
      const _Float16* kg = kh + ((size_t)bh * NN + kt * 64 + srow) * DHH + scol;
      *(half8*)&Kt[srow][scol]     = *(const half8*)(kg);
      *(half8*)&Kt[srow][scol + 8] = *(const half8*)(kg + 8);
      const _Float16* vg = vth + ((size_t)bh * DHH + srow) * NN + kt * 64 + scol;
      *(half8*)&Vt[srow][scol]     = *(const half8*)(vg);
      *(half8*)&Vt[srow][scol + 8] = *(const half8*)(vg + 8);
    }
    __syncthreads();
    f32x4 sc4[4];
#pragma unroll
    for (int nt = 0; nt < 4; ++nt) {
      half8 kfA = *(const half8*)&Kt[nt * 16 + l16][quad * 8];
      half8 kfB = *(const half8*)&Kt[nt * 16 + l16][32 + quad * 8];
      f32x4 z = {};
      z = __builtin_amdgcn_mfma_f32_16x16x32_f16(qf0, kfA, z, 0, 0, 0);
      sc4[nt] = __builtin_amdgcn_mfma_f32_16x16x32_f16(qf1, kfB, z, 0, 0, 0);
    }
    if (kt == qi) {
#pragma unroll
      for (int nt = 0; nt < 4; ++nt) {
        int key = nt * 16 + l16;
#pragma unroll
        for (int r = 0; r < 4; ++r)
          if (key > wv * 16 + quad * 4 + r) sc4[nt][r] = -1e30f;
      }
    }
    float rm[4];
#pragma unroll
    for (int r = 0; r < 4; ++r)
      rm[r] = fmaxf(fmaxf(sc4[0][r], sc4[1][r]), fmaxf(sc4[2][r], sc4[3][r]));
#pragma unroll
    for (int off = 1; off < 16; off <<= 1)
#pragma unroll
      for (int r = 0; r < 4; ++r)
        rm[r] = fmaxf(rm[r], __shfl_xor(rm[r], off, 64));
    float alpha[4], rs[4];
#pragma unroll
    for (int r = 0; r < 4; ++r) {
      float mn = fmaxf(mrow[r], rm[r]);
      alpha[r] = __expf(mrow[r] - mn);
      mrow[r] = mn;
      rs[r] = 0.f;
    }
#pragma unroll
    for (int nt = 0; nt < 4; ++nt)
#pragma unroll
      for (int r = 0; r < 4; ++r) {
        float p = __expf(sc4[nt][r] - mrow[r]);
        rs[r] += p;
        Pb[wv * 16 + quad * 4 + r][nt * 16 + l16] = (_Float16)p;
      }
#pragma unroll
    for (int off = 1; off < 16; off <<= 1)
#pragma unroll
      for (int r = 0; r < 4; ++r)
        rs[r] += __shfl_xor(rs[r], off, 64);
#pragma unroll
    for (int r = 0; r < 4; ++r) lrow[r] = lrow[r] * alpha[r] + rs[r];
#pragma unroll
    for (int nt = 0; nt < 4; ++nt)
#pragma unroll
      for (int r = 0; r < 4; ++r) o[nt][r] *= alpha[r];
    asm volatile("s_waitcnt lgkmcnt(0)" ::: "memory");
    half8 pf0 = *(const half8*)&Pb[wv * 16 + l16][quad * 8];
    half8 pf1 = *(const half8*)&Pb[wv * 16 + l16][32 + quad * 8];
#pragma unroll
    for (int nt = 0; nt < 4; ++nt) {
      half8 vfA = *(const half8*)&Vt[nt * 16 + l16][quad * 8];
      half8 vfB = *(const half8*)&Vt[nt * 16 + l16][32 + quad * 8];
      o[nt] = __builtin_amdgcn_mfma_f32_16x16x32_f16(pf0, vfA, o[nt], 0, 0, 0);
      o[nt] = __builtin_amdgcn_mfma_f32_16x16x32_f16(pf1, vfB, o[nt], 0, 0, 0);
    }
  }
  int b = bh >> 4, h = bh & 15;
#pragma unroll
  for (int r = 0; r < 4; ++r) {
    float inv = 1.f / lrow[r];
    int pos = q0 + wv * 16 + quad * 4 + r;
    size_t ob = ((size_t)(b * NN + pos)) * DIMM + h * DHH;
#pragma unroll
    for (int nt = 0; nt < 4; ++nt)
      ah[ob + nt * 16 + l16] = (_Float16)(o[nt][r] * inv);
  }
}

// ---------------- out GEMM (MFMA f16) + bias ----------------
__global__ __launch_bounds__(256) void gemm_out_kernel(
    const _Float16* __restrict__ ah, const _Float16* __restrict__ wot,
    const float* __restrict__ bo, float* __restrict__ out) {
  __shared__ _Float16 At[64][40];
  __shared__ _Float16 Bt[64][40];
  int m0 = blockIdx.x * 64;
  int n0 = blockIdx.y * 64;
  int t = threadIdx.x;
  int wv = t >> 6;
  int lane = t & 63;
  int l16 = lane & 15;
  int quad = lane >> 4;
  int sr = t >> 2;
  int sc = (t & 3) * 8;
  f32x4 acc[4] = {};
  const _Float16* ap = ah + (size_t)(m0 + sr) * 1024 + sc;
  const _Float16* bp = wot + (size_t)(n0 + sr) * 1024 + sc;
  for (int k0 = 0; k0 < 1024; k0 += 32) {
    half8 av = *(const half8*)(ap + k0);
    half8 bv = *(const half8*)(bp + k0);
    *(half8*)(&At[sr][sc]) = av;
    *(half8*)(&Bt[sr][sc]) = bv;
    __syncthreads();
    half8 af = *(const half8*)(&At[wv * 16 + l16][quad * 8]);
#pragma unroll
    for (int nt = 0; nt < 4; ++nt) {
      half8 bf = *(const half8*)(&Bt[nt * 16 + l16][quad * 8]);
      acc[nt] = __builtin_amdgcn_mfma_f32_16x16x32_f16(af, bf, acc[nt], 0, 0, 0);
    }
    __syncthreads();
  }
#pragma unroll
  for (int nt = 0; nt < 4; ++nt) {
    int col = n0 + nt * 16 + l16;
    float bias = bo[col];
#pragma unroll
    for (int rr = 0; rr < 4; ++rr) {
      out[(size_t)(m0 + wv * 16 + quad * 4 + rr) * 1024 + col] = acc[nt][rr] + bias;
    }
  }
}

extern "C" void kernel_launch(void* const* d_in, const int* in_sizes, int n_in,
                              void* d_out, int out_size, void* d_ws, size_t ws_size,
                              hipStream_t stream) {
  (void)in_sizes; (void)n_in; (void)out_size; (void)ws_size;
  const float* x  = (const float*)d_in[0];
  const float* Wq = (const float*)d_in[1];
  const float* Wk = (const float*)d_in[2];
  const float* Wv = (const float*)d_in[3];
  const float* Wo = (const float*)d_in[4];
  const float* bo = (const float*)d_in[5];

  float* out = (float*)d_out;
  float* ko  = out + (size_t)MMR * DIMM;
  float* vo  = ko + (size_t)BB * NHH * NN * DHH;

  char* w = (char*)d_ws;
  _Float16* xh  = (_Float16*)w;                   // 8 MB (dead after gemm_qkv)
  _Float16* ah  = (_Float16*)w;                   // 8 MB (reuses xh region)
  _Float16* wt  = (_Float16*)(w + (8u << 20));    // 8 MB
  _Float16* qh  = (_Float16*)(w + (16u << 20));   // 8 MB (b,h,n,dh) roped, *0.125
  _Float16* kh  = (_Float16*)(w + (24u << 20));   // 8 MB (b,h,n,dh) roped
  _Float16* vth = (_Float16*)(w + (32u << 20));   // 8 MB (b,h,dh,n)

  hipLaunchKernelGGL(cvt_x_kernel, dim3(4096), dim3(256), 0, stream, x, xh);
  hipLaunchKernelGGL(transpose_w_kernel, dim3(16, 16, 4), dim3(256), 0, stream,
                     Wq, Wk, Wv, Wo, wt);
  hipLaunchKernelGGL(gemm_qkv_kernel, dim3(64, 48), dim3(256), 0, stream,
                     xh, wt, ko, vo, qh, kh, vth);
  hipLaunchKernelGGL(fattn_kernel, dim3(32, 32), dim3(256), 0, stream,
                     qh, kh, vth, ah);
  hipLaunchKernelGGL(gemm_out_kernel, dim3(64, 16), dim3(256), 0, stream,
                     ah, wt + (size_t)3 * 1024 * 1024, bo, out);
}